// Round 4
// baseline (431.196 us; speedup 1.0000x reference)
//
#include <hip/hip_runtime.h>
#include <stdint.h>

#define EPSF 1e-20f

typedef __attribute__((ext_vector_type(4))) int i32x4;
typedef __attribute__((ext_vector_type(16))) int i32x16;

// ===========================================================================
// Pass 1: fp32 -> packed sign bits via ballot (verified in R1; bit=1 means
// negative). Bit order within each 256-element block is a fixed permutation
// — identical for x and w rows, so the GEMM dot product is invariant.
// x and w fused into one launch.
// ===========================================================================
__global__ __launch_bounds__(256)
void binpack_kernel(const float* __restrict__ x, const float* __restrict__ w,
                    unsigned long long* __restrict__ xb,
                    unsigned long long* __restrict__ wb, int nxwave) {
    int gw = blockIdx.x * 4 + (threadIdx.x >> 6);
    const float* src;
    unsigned long long* dst;
    int wv;
    if (gw < nxwave) { src = x; dst = xb; wv = gw; }
    else             { src = w; dst = wb; wv = gw - nxwave; }
    int lane = threadIdx.x & 63;
    const float4* p = (const float4*)(src + (size_t)wv * 256);
    float4 v = p[lane];
    unsigned long long m0 = __ballot(v.x < -EPSF);
    unsigned long long m1 = __ballot(v.y < -EPSF);
    unsigned long long m2 = __ballot(v.z < -EPSF);
    unsigned long long m3 = __ballot(v.w < -EPSF);
    if (lane < 4) {
        unsigned long long m = (lane == 0) ? m0 : (lane == 1) ? m1
                             : (lane == 2) ? m2 : m3;
        dst[(size_t)wv * 4 + lane] = m;
    }
}

// ===========================================================================
// Pass 2: packed-bit GEMM. Stage 12 KB of PACKED bits per block-iter
// (BK = 256 elements = 8 dwords/row), expand bits -> ±1 i8 in registers
// (~7 full-rate VALU ops per i8x4 dword, no 32-bit muls), feed
// v_mfma_i32_32x32x32_i8. Block 256x128, 4 waves, wave tile 64x128
// (2x4 of 32x32). Staging is tiny -> the R3 barrier-drain stall vanishes.
// ===========================================================================
#define PM 256
#define PN 128

__device__ __forceinline__ uint32_t expand4(uint32_t nib) {
    // 4 sign bits (1=neg) -> 4 i8 bytes (0x01 / 0xFF).
    // __umul24(n,0x204081): n's 4 bits -> disjoint fields [0-3],[7-10],
    // [14-17],[21-24]; mask LSB of each byte; fill byte; OR in +1.
    uint32_t s = __umul24(nib, 0x204081u) & 0x01010101u;
    uint32_t f = s | (s << 1);
    f |= f << 2;
    f |= f << 4;              // bytes 0x00 or 0xFF (shifts never cross bytes)
    return f | 0x01010101u;   // 0x01 (+1) or 0xFF (-1)
}

__device__ __forceinline__ i32x4 expand16(uint32_t q) {
    i32x4 r;
    r[0] = (int)expand4(q & 15u);
    r[1] = (int)expand4((q >> 4) & 15u);
    r[2] = (int)expand4((q >> 8) & 15u);
    r[3] = (int)expand4((q >> 12) & 15u);
    return r;
}

__global__ __launch_bounds__(256, 2)
void pk_gemm(const char* __restrict__ xb, const char* __restrict__ wb,
             float* __restrict__ out) {
    __shared__ uint32_t xsp[PM * 8];   // 8 KB packed x tile
    __shared__ uint32_t wsp[PN * 8];   // 4 KB packed w tile

    const int t = threadIdx.x;
    const int lane = t & 63;
    const int wave = t >> 6;
    const int lrow = lane & 31;
    const int half = lane >> 5;
    const int hs = half * 16;          // this half consumes bits 16h..16h+15
    const int row0 = blockIdx.y * PM;
    const int col0 = blockIdx.x * PN;
    const int wm = wave * 64;

    i32x16 acc[2][4];
#pragma unroll
    for (int r = 0; r < 2; ++r)
#pragma unroll
        for (int c = 0; c < 4; ++c)
#pragma unroll
            for (int e = 0; e < 16; ++e) acc[r][c][e] = 0;

    // staging chunk assignment (16B chunks): x chunks t, t+256; w chunk t
    const int cx0 = t, cx1 = t + 256, cw = t;
    const int rx0 = cx0 >> 1, rx1 = cx1 >> 1, rw = cw >> 1;

    for (int kd = 0; kd < 128; kd += 8) {   // packed-dword offset within row
        __syncthreads();
        __builtin_amdgcn_global_load_lds(
            (const uint32_t*)(xb + (size_t)(row0 + rx0) * 512 + kd * 4 + (cx0 & 1) * 16),
            &xsp[cx0 * 4], 16, 0, 0);
        __builtin_amdgcn_global_load_lds(
            (const uint32_t*)(xb + (size_t)(row0 + rx1) * 512 + kd * 4 + (cx1 & 1) * 16),
            &xsp[cx1 * 4], 16, 0, 0);
        __builtin_amdgcn_global_load_lds(
            (const uint32_t*)(wb + (size_t)(col0 + rw) * 512 + kd * 4 + (cw & 1) * 16),
            &wsp[cw * 4], 16, 0, 0);
        __syncthreads();

#pragma unroll
        for (int hi = 0; hi < 2; ++hi) {
            i32x4 pax[2], pbx[4];
#pragma unroll
            for (int r = 0; r < 2; ++r)
                pax[r] = *(const i32x4*)&xsp[(wm + r * 32 + lrow) * 8 + hi * 4];
#pragma unroll
            for (int c = 0; c < 4; ++c)
                pbx[c] = *(const i32x4*)&wsp[(c * 32 + lrow) * 8 + hi * 4];

#pragma unroll
            for (int s = 0; s < 4; ++s) {
                i32x4 a[2], b[4];
#pragma unroll
                for (int r = 0; r < 2; ++r)
                    a[r] = expand16((uint32_t)pax[r][s] >> hs);
#pragma unroll
                for (int c = 0; c < 4; ++c)
                    b[c] = expand16((uint32_t)pbx[c][s] >> hs);
#pragma unroll
                for (int r = 0; r < 2; ++r)
#pragma unroll
                    for (int c = 0; c < 4; ++c)
                        acc[r][c] = __builtin_amdgcn_mfma_i32_32x32x32_i8(
                            a[r], b[c], acc[r][c], 0, 0, 0);
            }
        }
    }

    // C/D 32x32 layout (verified R2/R3): col = lane&31,
    // row = (e&3) + 8*(e>>2) + 4*(lane>>5)
#pragma unroll
    for (int r = 0; r < 2; ++r)
#pragma unroll
        for (int c = 0; c < 4; ++c)
#pragma unroll
            for (int e = 0; e < 16; ++e) {
                int rr = row0 + wm + r * 32 + (e & 3) + 8 * (e >> 2) + 4 * half;
                int cc = col0 + c * 32 + lrow;
                out[(size_t)rr * 4096 + cc] = (float)acc[r][c][e];
            }
}

// ===========================================================================
extern "C" void kernel_launch(void* const* d_in, const int* in_sizes, int n_in,
                              void* d_out, int out_size, void* d_ws, size_t ws_size,
                              hipStream_t stream) {
    const float* x = (const float*)d_in[0];   // [8192, 4096] fp32
    const float* w = (const float*)d_in[1];   // [4096, 4096] fp32
    float* out = (float*)d_out;

    const int M = 8192, N = 4096, K = 4096;

    // workspace: packed x (M*K/8 = 4 MB) then packed w (N*K/8 = 2 MB)
    char* xbits = (char*)d_ws;
    char* wbits = xbits + (size_t)M * (K / 8);

    int nxwave = (M * K) / 256;   // 131072
    int nwwave = (N * K) / 256;   // 65536
    binpack_kernel<<<(nxwave + nwwave) / 4, 256, 0, stream>>>(
        x, w, (unsigned long long*)xbits, (unsigned long long*)wbits, nxwave);

    dim3 grid(N / PN, M / PM);    // (32, 32)
    pk_gemm<<<grid, 256, 0, stream>>>(xbits, wbits, out);
}